// Round 13
// baseline (651.482 us; speedup 1.0000x reference)
//
#include <hip/hip_runtime.h>

typedef _Float16 half8 __attribute__((ext_vector_type(8)));
typedef float f32x4 __attribute__((ext_vector_type(4)));

#define B_TOTAL 32768
#define T 7
#define F 36
#define U 256
#define G4 1024
#define BM 64          // per block; two halves of 32 rows (A=0..31, B=32..63)
#define THREADS 512    // 8 waves; __launch_bounds__(512,2) -> 256 reg/wave budget
#define KC 10          // K chunks of 32: kc 0..7 = h (K=256), kc 8..9 = x (F padded)
#define KPACK 32
#define H_STRIDE 264   // halves; 528 B rows, 16B-aligned
#define XS 72          // halves per (t,row) in xs plane

// Verified W layout (rounds 0/5/11): Wq[kc][n][kin] fp16, n = gate*256 + u.
__global__ __launch_bounds__(1024) void pack_w(const float* __restrict__ Wr,
                                               const float* __restrict__ Wk,
                                               _Float16* __restrict__ Wq) {
    const int kc   = blockIdx.x >> 2;
    const int kin0 = (blockIdx.x & 3) * 8;
    const int n    = threadIdx.x;
    _Float16* dst = Wq + ((size_t)kc * G4 + n) * KPACK + kin0;
    #pragma unroll
    for (int j = 0; j < 8; ++j) {
        int k = kc * KPACK + kin0 + j;
        float v = 0.f;
        if (k < U)          v = Wr[(size_t)k * G4 + n];
        else if (k < U + F) v = Wk[(size_t)(k - U) * G4 + n];
        dst[j] = (_Float16)v;
    }
}

__device__ __forceinline__ float fast_sigmoid(float x) {
    return __builtin_amdgcn_rcpf(1.f + __expf(-x));
}
__device__ __forceinline__ float fast_tanh(float x) {
    return 1.f - 2.f * __builtin_amdgcn_rcpf(1.f + __expf(2.f * x));
}

// Two-half software-pipelined persistent LSTM.
// 8 waves, wave w owns u-tile [32w,32w+32) x 4 gates. Per half: acc[2 mt][8 gnt]
// (gnt=g*2+nt). Each barrier-free segment = K(one half) + gates(other half):
// independent chains -> scheduler interleaves MFMA/loads with trans VALU.
// Register budget: 512thr @ min 2 waves/EU -> 256 regs; pA+pB+c+temps ~ 220.
// (Rounds 6/10 lesson: at 1024thr/128regs ANY liveness extension spills.)
__global__ __launch_bounds__(512, 2) void lstm_kernel(
    const float* __restrict__ x,      // [B,T,F]
    const float* __restrict__ h0,     // [B,U]
    const float* __restrict__ c0,     // [B,U]
    const _Float16* __restrict__ Wq,  // packed [KC][G4][KPACK]
    const float* __restrict__ bias_g, // [G4]
    float* __restrict__ out)          // [B,T,U]
{
    __shared__ __align__(16) _Float16 hA[2][32 * H_STRIDE];   // 2 x 16.9 KB
    __shared__ __align__(16) _Float16 hB[2][32 * H_STRIDE];   // 2 x 16.9 KB
    __shared__ __align__(16) _Float16 xs[T * BM * XS];        // 64.5 KB

    const int tid  = threadIdx.x;
    const int lane = tid & 63;
    const int w    = tid >> 6;     // wave id 0..7 = u-tile
    const int l15  = lane & 15;
    const int q    = lane >> 4;    // 0..3
    const int u0   = w * 32;
    const int b0   = blockIdx.x * BM;

    // --- zero xs (covers f=36..63 pad) ---
    {
        half8 z = {};
        for (int i = tid * 8; i < T * BM * XS; i += THREADS * 8)
            *(half8*)&xs[i] = z;
    }
    __syncthreads();

    // --- stage h0 -> halves ---
    for (int i = tid; i < BM * U; i += THREADS) {
        int m = i >> 8, u = i & 255;
        _Float16 v = (_Float16)h0[(size_t)b0 * U + i];
        if (m < 32) hA[0][m * H_STRIDE + u] = v;
        else        hB[0][(m - 32) * H_STRIDE + u] = v;
    }
    // --- stage ALL x ---
    for (int i = tid; i < BM * (T * F); i += THREADS) {
        int row = i / (T * F);
        int rem = i - row * (T * F);
        int t   = rem / F;
        int f   = rem - t * F;
        xs[(t * BM + row) * XS + f] = (_Float16)x[(size_t)(b0 + row) * (T * F) + rem];
    }
    // --- c0: per half, lane holds (u = u0+nt*16+l15), rows mt*16+q*4+r ---
    float cA[16], cB[16];
    #pragma unroll
    for (int mt = 0; mt < 2; ++mt)
        #pragma unroll
        for (int nt = 0; nt < 2; ++nt)
            #pragma unroll
            for (int r = 0; r < 4; ++r) {
                int idx = mt * 8 + nt * 4 + r;
                int row = mt * 16 + q * 4 + r;
                int u   = u0 + nt * 16 + l15;
                cA[idx] = c0[(size_t)(b0 + row) * U + u];
                cB[idx] = c0[(size_t)(b0 + 32 + row) * U + u];
            }
    float bv[4][2];
    #pragma unroll
    for (int g = 0; g < 4; ++g)
        #pragma unroll
        for (int nt = 0; nt < 2; ++nt)
            bv[g][nt] = bias_g[g * 256 + u0 + nt * 16 + l15];

    __syncthreads();   // staging complete

    f32x4 pA[2][8], pB[2][8];   // [m_tile][gnt], gnt = g*2+nt

    // K for one half: init acc with bias, accumulate h@Wr (kc<8 from hbase LDS)
    // and x_t@Wk (kc 8,9 from xs at xrow0).
    auto kstep = [&](f32x4 (&P)[2][8], const _Float16* hbase, int xrow0) {
        #pragma unroll
        for (int mt = 0; mt < 2; ++mt)
            #pragma unroll
            for (int gnt = 0; gnt < 8; ++gnt) {
                float v = bv[gnt >> 1][gnt & 1];
                P[mt][gnt] = (f32x4){v, v, v, v};
            }
        #pragma unroll 2
        for (int kc = 0; kc < KC; ++kc) {
            half8 af[2];
            #pragma unroll
            for (int mt = 0; mt < 2; ++mt) {
                if (kc < 8)
                    af[mt] = *(const half8*)&hbase[(mt * 16 + l15) * H_STRIDE + kc * 32 + q * 8];
                else
                    af[mt] = *(const half8*)&xs[(size_t)(xrow0 + mt * 16 + l15) * XS + (kc - 8) * 32 + q * 8];
            }
            #pragma unroll
            for (int bb = 0; bb < 2; ++bb) {
                half8 bf[4];
                #pragma unroll
                for (int j = 0; j < 4; ++j) {
                    int gnt = bb * 4 + j;
                    size_t off = ((size_t)kc * G4 + (gnt >> 1) * 256 + u0 + (gnt & 1) * 16 + l15) * KPACK + q * 8;
                    bf[j] = *(const half8*)(Wq + off);
                }
                #pragma unroll
                for (int mt = 0; mt < 2; ++mt)
                    #pragma unroll
                    for (int j = 0; j < 4; ++j)
                        P[mt][bb * 4 + j] = __builtin_amdgcn_mfma_f32_16x16x32_f16(af[mt], bf[j], P[mt][bb * 4 + j], 0, 0, 0);
            }
        }
    };

    // gates for one half: consume P, update c, write h fp16 to hnxt.
    auto gates = [&](f32x4 (&P)[2][8], float (&cc)[16], _Float16* hnxt) {
        #pragma unroll
        for (int mt = 0; mt < 2; ++mt)
            #pragma unroll
            for (int nt = 0; nt < 2; ++nt)
                #pragma unroll
                for (int r = 0; r < 4; ++r) {
                    int idx = mt * 8 + nt * 4 + r;
                    float zi = P[mt][0 + nt][r];
                    float zf = P[mt][2 + nt][r];
                    float zg = P[mt][4 + nt][r];
                    float zo = P[mt][6 + nt][r];
                    float ig = fast_sigmoid(zi);
                    float fg = fast_sigmoid(zf);
                    float gg = fast_tanh(zg);
                    float og = fast_sigmoid(zo);
                    float cn = fg * cc[idx] + ig * gg;
                    cc[idx] = cn;
                    float hv = og * fast_tanh(cn);
                    hnxt[(mt * 16 + q * 4 + r) * H_STRIDE + u0 + nt * 16 + l15] = (_Float16)hv;
                }
    };

    // coalesced nt out-store (readback): 32 rows x 256 u fp32 = 1024 chunks of 8.
    auto outst = [&](const _Float16* hsrc, int halfbase, int t) {
        #pragma unroll
        for (int rb = 0; rb < 2; ++rb) {
            int j   = tid + rb * THREADS;   // 0..1023
            int row = j >> 5;
            int uo  = (j & 31) * 8;
            half8 hv = *(const half8*)&hsrc[row * H_STRIDE + uo];
            f32x4 lo = { (float)hv[0], (float)hv[1], (float)hv[2], (float)hv[3] };
            f32x4 hi = { (float)hv[4], (float)hv[5], (float)hv[6], (float)hv[7] };
            float* dst = out + ((size_t)(b0 + halfbase + row) * T + t) * U + uo;
            __builtin_nontemporal_store(lo, (f32x4*)dst);
            __builtin_nontemporal_store(hi, (f32x4*)(dst + 4));
        }
    };

    int curA = 0, curB = 0;

    kstep(pA, hA[0], 0);    // K(A, t=0)

    #pragma unroll 1
    for (int t = 0; t < T; ++t) {
        // --- segment alpha: K(B,t) || gates(A,t) -> hA[curA^1] ---
        kstep(pB, hB[curB], t * BM + 32);
        gates(pA, cA, hA[curA ^ 1]);
        __syncthreads();                  // hA[curA^1] visible
        outst(hA[curA ^ 1], 0, t);        // fire-and-forget over segment beta
        curA ^= 1;

        // --- segment beta: K(A,t+1) || gates(B,t) -> hB[curB^1] ---
        if (t + 1 < T) kstep(pA, hA[curA], (t + 1) * BM);
        gates(pB, cB, hB[curB ^ 1]);
        __syncthreads();                  // hB[curB^1] visible
        outst(hB[curB ^ 1], 32, t);       // fire-and-forget over next alpha
        curB ^= 1;
    }
}

extern "C" void kernel_launch(void* const* d_in, const int* in_sizes, int n_in,
                              void* d_out, int out_size, void* d_ws, size_t ws_size,
                              hipStream_t stream) {
    const float* x  = (const float*)d_in[0];
    const float* h0 = (const float*)d_in[1];
    const float* c0 = (const float*)d_in[2];
    const float* Wk = (const float*)d_in[3];
    const float* Wr = (const float*)d_in[4];
    const float* b  = (const float*)d_in[5];
    float* out = (float*)d_out;

    _Float16* Wq = (_Float16*)d_ws;   // KC*G4*KPACK*2 = 640 KB

    pack_w<<<KC * 4, 1024, 0, stream>>>(Wr, Wk, Wq);
    lstm_kernel<<<B_TOTAL / BM, THREADS, 0, stream>>>(x, h0, c0, Wq, b, out);
}